// Round 1
// baseline (1403.040 us; speedup 1.0000x reference)
//
#include <hip/hip_runtime.h>

#define N_NODES 100000
#define N_EDGES 1600000
#define NUM_GRAPHS 128

// ---------------- degree accumulation ----------------
__global__ void deg_kernel(const int* __restrict__ src, const int* __restrict__ dst,
                           float* __restrict__ outdeg, float* __restrict__ indeg, int nE) {
    int i = blockIdx.x * 256 + threadIdx.x;
    if (i < nE) {
        atomicAdd(&outdeg[src[i]], 1.0f);
        atomicAdd(&indeg[dst[i]], 1.0f);
    }
}

__global__ void isq_kernel(float* __restrict__ d, int n) {
    int i = blockIdx.x * 256 + threadIdx.x;
    if (i < n) d[i] = rsqrtf(fmaxf(d[i], 1.0f));
}

// ---------------- edge scatter: agg[dst] += feat[src] * scale[src] ----------------
// one wave (64 lanes) per edge; lane = feature dim (D=69: lanes 0..4 do 2 dims)
template<int D>
__global__ void scatter_kernel(const float* __restrict__ feat, const int* __restrict__ src,
                               const int* __restrict__ dst, const float* __restrict__ sscale,
                               float* __restrict__ agg, int nE) {
    int wave = (int)(((unsigned)blockIdx.x * blockDim.x + threadIdx.x) >> 6);
    int lane = threadIdx.x & 63;
    if (wave >= nE) return;
    int s = src[wave], d = dst[wave];
    float sc = sscale[s];
    const float* fr = feat + (size_t)s * D;
    float* ar = agg + (size_t)d * D;
#pragma unroll
    for (int c = lane; c < D; c += 64)
        atomicAdd(&ar[c], fr[c] * sc);
}

// ---------------- dense per-node GEMM: out = [scale_row] * (in @ W), opt ReLU ----------------
// W staged in LDS (K*NO <= 8832 floats). 256 threads = (256/NO) rows x NO cols.
template<int K, int NO, bool SCALE, bool RELU>
__global__ __launch_bounds__(256) void node_gemm(const float* __restrict__ in,
                                                 const float* __restrict__ W,
                                                 const float* __restrict__ rowscale,
                                                 float* __restrict__ out, int nN) {
    __shared__ float Wl[K * NO];
    for (int i = threadIdx.x; i < K * NO; i += 256) Wl[i] = W[i];
    __syncthreads();

    const int RPP = 256 / NO;         // rows processed in parallel
    const int RB  = 16;               // rows per block
    int col  = threadIdx.x % NO;
    int rsub = threadIdx.x / NO;
    int row0 = blockIdx.x * RB;
    int rend = min(row0 + RB, nN);
    for (int r = row0 + rsub; r < rend; r += RPP) {
        const float* inr = in + (size_t)r * K;
        float acc = 0.0f;
#pragma unroll
        for (int k = 0; k < K; ++k)
            acc += inr[k] * Wl[k * NO + col];
        if (SCALE) acc *= rowscale[r];
        if (RELU)  acc = fmaxf(acc, 0.0f);
        out[(size_t)r * NO + col] = acc;
    }
}

// ---------------- fused scale+ReLU+segment-max readout ----------------
// one wave per 8 consecutive nodes (graph_ids sorted -> few atomics); lane = col (64 cols)
__global__ void readout_kernel(const float* __restrict__ agg2, const float* __restrict__ isqi,
                               const int* __restrict__ gid, unsigned* __restrict__ out, int nN) {
    const int NPW = 8;
    int wave = (int)(((unsigned)blockIdx.x * blockDim.x + threadIdx.x) >> 6);
    int lane = threadIdx.x & 63;
    int n0 = wave * NPW;
    if (n0 >= nN) return;
    int curg = gid[n0];
    float best = 0.0f;
    for (int i = 0; i < NPW; ++i) {
        int n = n0 + i;
        if (n >= nN) break;
        int g = gid[n];
        float v = fmaxf(agg2[(size_t)n * 64 + lane] * isqi[n], 0.0f);
        if (g != curg) {
            atomicMax(&out[curg * 64 + lane], __float_as_uint(best));
            curg = g;
            best = v;
        } else {
            best = fmaxf(best, v);
        }
    }
    atomicMax(&out[curg * 64 + lane], __float_as_uint(best));
}

extern "C" void kernel_launch(void* const* d_in, const int* in_sizes, int n_in,
                              void* d_out, int out_size, void* d_ws, size_t ws_size,
                              hipStream_t stream) {
    const float* x   = (const float*)d_in[0];   // [100000, 69]
    const float* W1  = (const float*)d_in[1];   // [69, 128]
    const float* W2  = (const float*)d_in[2];   // [128, 64]
    const int*   src = (const int*)d_in[3];     // [1600000]
    const int*   dst = (const int*)d_in[4];     // [1600000]
    const int*   gid = (const int*)d_in[5];     // [100000] sorted

    float* ws   = (float*)d_ws;
    float* isqo = ws;                                   // [N]
    float* isqi = ws + N_NODES;                         // [N]
    float* bufA = ws + 2 * (size_t)N_NODES;             // 6.9M floats: agg1 -> y2
    float* bufB = bufA + (size_t)N_NODES * 69;          // 12.8M floats: h1 -> agg2

    // zero accumulators (must happen every call: graph replays don't re-poison)
    hipMemsetAsync(isqo, 0, 2 * (size_t)N_NODES * sizeof(float), stream);
    hipMemsetAsync(bufA, 0, (size_t)N_NODES * 69 * sizeof(float), stream);
    hipMemsetAsync(d_out, 0, (size_t)out_size * sizeof(float), stream);

    // degrees -> inverse sqrt
    deg_kernel<<<(N_EDGES + 255) / 256, 256, 0, stream>>>(src, dst, isqo, isqi, N_EDGES);
    isq_kernel<<<(2 * N_NODES + 255) / 256, 256, 0, stream>>>(isqo, 2 * N_NODES);

    // ----- layer 1: scatter (width 69) then GEMM(+scale+relu) -----
    {
        int waves = N_EDGES;                 // 1 wave per edge
        int blocks = (waves * 64 + 255) / 256;
        scatter_kernel<69><<<blocks, 256, 0, stream>>>(x, src, dst, isqo, bufA, N_EDGES);
    }
    node_gemm<69, 128, true, true><<<(N_NODES + 15) / 16, 256, 0, stream>>>(bufA, W1, isqi, bufB, N_NODES);

    // ----- layer 2: GEMM first (width 128->64), then scatter (width 64) -----
    node_gemm<128, 64, false, false><<<(N_NODES + 15) / 16, 256, 0, stream>>>(bufB, W2, nullptr, bufA, N_NODES);
    hipMemsetAsync(bufB, 0, (size_t)N_NODES * 64 * sizeof(float), stream);  // agg2 (reuses h1 space)
    {
        int waves = N_EDGES;
        int blocks = (waves * 64 + 255) / 256;
        scatter_kernel<64><<<blocks, 256, 0, stream>>>(bufA, src, dst, isqo, bufB, N_EDGES);
    }

    // ----- fused scale + ReLU + per-graph max readout -----
    {
        int waves = (N_NODES + 7) / 8;
        int blocks = (waves * 64 + 255) / 256;
        readout_kernel<<<blocks, 256, 0, stream>>>(bufB, isqi, gid, (unsigned*)d_out, N_NODES);
    }
}

// Round 2
// 861.205 us; speedup vs baseline: 1.6292x; 1.6292x over previous
//
#include <hip/hip_runtime.h>

#define N_NODES 100000
#define N_EDGES 1600000
#define NUM_GRAPHS 128
#define SCAN_BS 1024

// ---------------- histogram: in/out degree (int) ----------------
__global__ void hist_kernel(const int* __restrict__ src, const int* __restrict__ dst,
                            int* __restrict__ cnt_src, int* __restrict__ cnt_dst, int nE) {
    int i = blockIdx.x * 256 + threadIdx.x;
    if (i < nE) {
        atomicAdd(&cnt_src[src[i]], 1);
        atomicAdd(&cnt_dst[dst[i]], 1);
    }
}

__global__ void isq_from_cnt(const int* __restrict__ cnt, float* __restrict__ out, int n) {
    int i = blockIdx.x * 256 + threadIdx.x;
    if (i < n) out[i] = rsqrtf(fmaxf((float)cnt[i], 1.0f));
}

// ---------------- exclusive scan (3 kernels) ----------------
__global__ __launch_bounds__(256) void scan1(const int* __restrict__ cnt, int* __restrict__ excl,
                                             int* __restrict__ blksum, int n) {
    __shared__ int tmp[256];
    int t = threadIdx.x;
    int base = blockIdx.x * SCAN_BS;
    int idx0 = base + t * 4;
    int v[4];
#pragma unroll
    for (int k = 0; k < 4; ++k) { int i = idx0 + k; v[k] = (i < n) ? cnt[i] : 0; }
    int sum = v[0] + v[1] + v[2] + v[3];
    tmp[t] = sum;
    __syncthreads();
    for (int off = 1; off < 256; off <<= 1) {
        int y = (t >= off) ? tmp[t - off] : 0;
        __syncthreads();
        tmp[t] += y;
        __syncthreads();
    }
    int run = (t > 0) ? tmp[t - 1] : 0;
#pragma unroll
    for (int k = 0; k < 4; ++k) { int i = idx0 + k; if (i < n) excl[i] = run; run += v[k]; }
    if (t == 255) blksum[blockIdx.x] = tmp[255];
}

__global__ void scan2(int* __restrict__ blksum, int nb) {
    if (threadIdx.x == 0 && blockIdx.x == 0) {
        int run = 0;
        for (int i = 0; i < nb; ++i) { int v = blksum[i]; blksum[i] = run; run += v; }
    }
}

__global__ void scan3(int* __restrict__ excl, const int* __restrict__ blkoff,
                      int* __restrict__ cursor, int n) {
    int i = blockIdx.x * 256 + threadIdx.x;
    if (i < n) {
        int v = excl[i] + blkoff[i >> 10];
        excl[i] = v;
        cursor[i] = v;
    }
}

// ---------------- edge reorder into dst-CSR ----------------
__global__ void reorder_kernel(const int* __restrict__ src, const int* __restrict__ dst,
                               int* __restrict__ cursor, int* __restrict__ ecol, int nE) {
    int i = blockIdx.x * 256 + threadIdx.x;
    if (i < nE) {
        int pos = atomicAdd(&cursor[dst[i]], 1);
        ecol[pos] = src[i];
    }
}

// ---------------- gather: agg[n] = isqi[n] * sum_{e in row n} feat[src_e]*isqo[src_e] ----------------
// one wave per dst node; lane = feature dim
template<int D>
__global__ void gather_kernel(const float* __restrict__ feat, const int* __restrict__ ecol,
                              const int* __restrict__ row_start, const float* __restrict__ sscale,
                              const float* __restrict__ dscale, float* __restrict__ agg,
                              int nN, int nE) {
    int wave = (int)(((unsigned)blockIdx.x * blockDim.x + threadIdx.x) >> 6);
    int lane = threadIdx.x & 63;
    if (wave >= nN) return;
    int beg = row_start[wave];
    int end = (wave == nN - 1) ? nE : row_start[wave + 1];
    float acc0 = 0.0f, acc1 = 0.0f;
    for (int j0 = beg; j0 < end; j0 += 64) {
        int ne = min(64, end - j0);
        int eidx = (lane < ne) ? ecol[j0 + lane] : 0;
        for (int k = 0; k < ne; ++k) {
            int s = __shfl(eidx, k);
            float sc = sscale[s];
            const float* fr = feat + (size_t)s * D;
            acc0 += fr[lane] * sc;
            if (D > 64 && lane < D - 64) acc1 += fr[64 + lane] * sc;
        }
    }
    float dsc = dscale[wave];
    agg[(size_t)wave * D + lane] = acc0 * dsc;
    if (D > 64 && lane < D - 64) agg[(size_t)wave * D + 64 + lane] = acc1 * dsc;
}

// ---------------- dense per-node GEMM: out = in @ W, opt ReLU ----------------
template<int K, int NO, bool RELU>
__global__ __launch_bounds__(256) void node_gemm(const float* __restrict__ in,
                                                 const float* __restrict__ W,
                                                 float* __restrict__ out, int nN) {
    __shared__ float Wl[K * NO];
    for (int i = threadIdx.x; i < K * NO; i += 256) Wl[i] = W[i];
    __syncthreads();

    const int RPP = 256 / NO;
    const int RB  = 16;
    int col  = threadIdx.x % NO;
    int rsub = threadIdx.x / NO;
    int row0 = blockIdx.x * RB;
    int rend = min(row0 + RB, nN);
    for (int r = row0 + rsub; r < rend; r += RPP) {
        const float* inr = in + (size_t)r * K;
        float acc = 0.0f;
#pragma unroll
        for (int k = 0; k < K; ++k)
            acc += inr[k] * Wl[k * NO + col];
        if (RELU) acc = fmaxf(acc, 0.0f);
        out[(size_t)r * NO + col] = acc;
    }
}

// ---------------- fused ReLU + per-graph max readout ----------------
__global__ void readout_kernel(const float* __restrict__ agg2, const int* __restrict__ gid,
                               unsigned* __restrict__ out, int nN) {
    const int NPW = 8;
    int wave = (int)(((unsigned)blockIdx.x * blockDim.x + threadIdx.x) >> 6);
    int lane = threadIdx.x & 63;
    int n0 = wave * NPW;
    if (n0 >= nN) return;
    int curg = gid[n0];
    float best = 0.0f;
    for (int i = 0; i < NPW; ++i) {
        int n = n0 + i;
        if (n >= nN) break;
        int g = gid[n];
        float v = fmaxf(agg2[(size_t)n * 64 + lane], 0.0f);
        if (g != curg) {
            atomicMax(&out[curg * 64 + lane], __float_as_uint(best));
            curg = g;
            best = v;
        } else {
            best = fmaxf(best, v);
        }
    }
    atomicMax(&out[curg * 64 + lane], __float_as_uint(best));
}

extern "C" void kernel_launch(void* const* d_in, const int* in_sizes, int n_in,
                              void* d_out, int out_size, void* d_ws, size_t ws_size,
                              hipStream_t stream) {
    const float* x   = (const float*)d_in[0];   // [100000, 69]
    const float* W1  = (const float*)d_in[1];   // [69, 128]
    const float* W2  = (const float*)d_in[2];   // [128, 64]
    const int*   src = (const int*)d_in[3];     // [1600000]
    const int*   dst = (const int*)d_in[4];     // [1600000]
    const int*   gid = (const int*)d_in[5];     // [100000] sorted

    const int NB_SCAN = (N_NODES + SCAN_BS - 1) / SCAN_BS;  // 98

    char* w = (char*)d_ws;
    float* isqo    = (float*)w;                 w += N_NODES * 4;
    float* isqi    = (float*)w;                 w += N_NODES * 4;
    int* cnt_src   = (int*)w;                   w += N_NODES * 4;
    int* cnt_dst   = (int*)w;                   w += N_NODES * 4;
    int* row_start = (int*)w;                   w += N_NODES * 4;
    int* cursor    = (int*)w;                   w += N_NODES * 4;
    int* blksum    = (int*)w;                   w += ((NB_SCAN + 255) / 256) * 1024;
    int* ecol      = (int*)w;                   w += (size_t)N_EDGES * 4;
    float* bufA    = (float*)w;                 w += (size_t)N_NODES * 69 * 4;  // agg1 -> y2
    float* bufB    = (float*)w;                 /* [N,128] h1 -> [N,64] agg2 */

    // zero int accumulators + output (every call: graph replays don't re-poison)
    hipMemsetAsync(cnt_src, 0, 2 * (size_t)N_NODES * sizeof(int), stream);
    hipMemsetAsync(d_out, 0, (size_t)out_size * sizeof(float), stream);

    // ----- CSR build + degree scales -----
    hist_kernel<<<(N_EDGES + 255) / 256, 256, 0, stream>>>(src, dst, cnt_src, cnt_dst, N_EDGES);
    isq_from_cnt<<<(N_NODES + 255) / 256, 256, 0, stream>>>(cnt_src, isqo, N_NODES);
    isq_from_cnt<<<(N_NODES + 255) / 256, 256, 0, stream>>>(cnt_dst, isqi, N_NODES);
    scan1<<<NB_SCAN, 256, 0, stream>>>(cnt_dst, row_start, blksum, N_NODES);
    scan2<<<1, 64, 0, stream>>>(blksum, NB_SCAN);
    scan3<<<(N_NODES + 255) / 256, 256, 0, stream>>>(row_start, blksum, cursor, N_NODES);
    reorder_kernel<<<(N_EDGES + 255) / 256, 256, 0, stream>>>(src, dst, cursor, ecol, N_EDGES);

    // ----- layer 1: gather (width 69, scales fused) then GEMM(+relu) -----
    gather_kernel<69><<<(N_NODES * 64 + 255) / 256, 256, 0, stream>>>(
        x, ecol, row_start, isqo, isqi, bufA, N_NODES, N_EDGES);
    node_gemm<69, 128, true><<<(N_NODES + 15) / 16, 256, 0, stream>>>(bufA, W1, bufB, N_NODES);

    // ----- layer 2: GEMM first (128->64), then gather (width 64, scales fused) -----
    node_gemm<128, 64, false><<<(N_NODES + 15) / 16, 256, 0, stream>>>(bufB, W2, bufA, N_NODES);
    gather_kernel<64><<<(N_NODES * 64 + 255) / 256, 256, 0, stream>>>(
        bufA, ecol, row_start, isqo, isqi, bufB, N_NODES, N_EDGES);

    // ----- fused ReLU + per-graph max readout -----
    readout_kernel<<<((N_NODES + 7) / 8 * 64 + 255) / 256, 256, 0, stream>>>(
        bufB, gid, (unsigned*)d_out, N_NODES);
}

// Round 3
// 592.082 us; speedup vs baseline: 2.3697x; 1.4545x over previous
//
#include <hip/hip_runtime.h>

#define N_NODES 100000
#define N_EDGES 1600000
#define NUM_GRAPHS 128
#define SCAN_BS 1024

// ---------------- histogram: in/out degree (int) ----------------
__global__ void hist_kernel(const int* __restrict__ src, const int* __restrict__ dst,
                            int* __restrict__ cnt_src, int* __restrict__ cnt_dst, int nE) {
    int i = blockIdx.x * 256 + threadIdx.x;
    if (i < nE) {
        atomicAdd(&cnt_src[src[i]], 1);
        atomicAdd(&cnt_dst[dst[i]], 1);
    }
}

__global__ void isq_from_cnt(const int* __restrict__ cnt, float* __restrict__ out, int n) {
    int i = blockIdx.x * 256 + threadIdx.x;
    if (i < n) out[i] = rsqrtf(fmaxf((float)cnt[i], 1.0f));
}

// ---------------- exclusive scan (3 kernels) ----------------
__global__ __launch_bounds__(256) void scan1(const int* __restrict__ cnt, int* __restrict__ excl,
                                             int* __restrict__ blksum, int n) {
    __shared__ int tmp[256];
    int t = threadIdx.x;
    int base = blockIdx.x * SCAN_BS;
    int idx0 = base + t * 4;
    int v[4];
#pragma unroll
    for (int k = 0; k < 4; ++k) { int i = idx0 + k; v[k] = (i < n) ? cnt[i] : 0; }
    int sum = v[0] + v[1] + v[2] + v[3];
    tmp[t] = sum;
    __syncthreads();
    for (int off = 1; off < 256; off <<= 1) {
        int y = (t >= off) ? tmp[t - off] : 0;
        __syncthreads();
        tmp[t] += y;
        __syncthreads();
    }
    int run = (t > 0) ? tmp[t - 1] : 0;
#pragma unroll
    for (int k = 0; k < 4; ++k) { int i = idx0 + k; if (i < n) excl[i] = run; run += v[k]; }
    if (t == 255) blksum[blockIdx.x] = tmp[255];
}

__global__ void scan2(int* __restrict__ blksum, int nb) {
    if (threadIdx.x == 0 && blockIdx.x == 0) {
        int run = 0;
        for (int i = 0; i < nb; ++i) { int v = blksum[i]; blksum[i] = run; run += v; }
    }
}

__global__ void scan3(int* __restrict__ excl, const int* __restrict__ blkoff,
                      int* __restrict__ cursor, int n) {
    int i = blockIdx.x * 256 + threadIdx.x;
    if (i < n) {
        int v = excl[i] + blkoff[i >> 10];
        excl[i] = v;
        cursor[i] = v;
    }
}

// ---------------- edge reorder into dst-CSR ----------------
__global__ void reorder_kernel(const int* __restrict__ src, const int* __restrict__ dst,
                               int* __restrict__ cursor, int* __restrict__ ecol, int nE) {
    int i = blockIdx.x * 256 + threadIdx.x;
    if (i < nE) {
        int pos = atomicAdd(&cursor[dst[i]], 1);
        ecol[pos] = src[i];
    }
}

// ---------------- gather: agg[n] = isqi[n] * sum_{e in row n} feat[src_e]*isqo[src_e] ----------------
// one wave per dst node; lane = feature dim. Output stride DS (pad cols D..DS-1 zeroed).
template<int D, int DS>
__global__ void gather_kernel(const float* __restrict__ feat, const int* __restrict__ ecol,
                              const int* __restrict__ row_start, const float* __restrict__ sscale,
                              const float* __restrict__ dscale, float* __restrict__ agg,
                              int nN, int nE) {
    int wave = (int)(((unsigned)blockIdx.x * blockDim.x + threadIdx.x) >> 6);
    int lane = threadIdx.x & 63;
    if (wave >= nN) return;
    int beg = row_start[wave];
    int end = (wave == nN - 1) ? nE : row_start[wave + 1];
    float acc0 = 0.0f, acc1 = 0.0f;
    for (int j0 = beg; j0 < end; j0 += 64) {
        int ne = min(64, end - j0);
        int eidx = (lane < ne) ? ecol[j0 + lane] : 0;
        for (int k = 0; k < ne; ++k) {
            int s = __shfl(eidx, k);
            float sc = sscale[s];
            const float* fr = feat + (size_t)s * D;
            acc0 += fr[lane] * sc;
            if (D > 64 && lane < D - 64) acc1 += fr[64 + lane] * sc;
        }
    }
    float dsc = dscale[wave];
    agg[(size_t)wave * DS + lane] = acc0 * dsc;
    if (DS > 64) {
        if (lane < DS - 64)
            agg[(size_t)wave * DS + 64 + lane] = (lane < D - 64) ? acc1 * dsc : 0.0f;
    }
}

// ---------------- register-blocked node GEMM: out[N][NO] = in[N][KP(valid K)] @ W[K][NO] ----------------
// 256 threads; thread = (rt, cg): 4 rows x 8 cols micro-tile. W staged in LDS (rows K..KP-1 zero).
template<int KP, int K, int NO, bool RELU>
__global__ __launch_bounds__(256) void node_gemm(const float* __restrict__ in,
                                                 const float* __restrict__ W,
                                                 float* __restrict__ out, int nN) {
    constexpr int CG = NO / 8;          // col groups
    constexpr int RT = 256 / CG;        // row threads
    constexpr int ROWS = RT * 4;        // rows per block
    __shared__ float Wl[KP * NO];
    for (int i = threadIdx.x; i < KP * NO; i += 256) {
        int k = i / NO;
        Wl[i] = (k < K) ? W[i] : 0.0f;
    }
    __syncthreads();

    int cg = threadIdx.x % CG;
    int rt = threadIdx.x / CG;
    int row0 = blockIdx.x * ROWS + rt * 4;
    int c0 = cg * 8;

    float4 accL[4] = {};
    float4 accH[4] = {};
    int rclamp[4];
#pragma unroll
    for (int r = 0; r < 4; ++r) rclamp[r] = min(row0 + r, nN - 1);

#pragma unroll 2
    for (int k4 = 0; k4 < KP / 4; ++k4) {
        float4 a[4];
#pragma unroll
        for (int r = 0; r < 4; ++r)
            a[r] = *(const float4*)(in + (size_t)rclamp[r] * KP + k4 * 4);
#pragma unroll
        for (int kk = 0; kk < 4; ++kk) {
            int k = k4 * 4 + kk;
            float4 wlo = *(const float4*)&Wl[k * NO + c0];
            float4 whi = *(const float4*)&Wl[k * NO + c0 + 4];
#pragma unroll
            for (int r = 0; r < 4; ++r) {
                float ar = (kk == 0) ? a[r].x : (kk == 1) ? a[r].y : (kk == 2) ? a[r].z : a[r].w;
                accL[r].x += ar * wlo.x; accL[r].y += ar * wlo.y;
                accL[r].z += ar * wlo.z; accL[r].w += ar * wlo.w;
                accH[r].x += ar * whi.x; accH[r].y += ar * whi.y;
                accH[r].z += ar * whi.z; accH[r].w += ar * whi.w;
            }
        }
    }

#pragma unroll
    for (int r = 0; r < 4; ++r) {
        int row = row0 + r;
        if (row < nN) {
            float4 lo = accL[r], hi = accH[r];
            if (RELU) {
                lo.x = fmaxf(lo.x, 0.f); lo.y = fmaxf(lo.y, 0.f);
                lo.z = fmaxf(lo.z, 0.f); lo.w = fmaxf(lo.w, 0.f);
                hi.x = fmaxf(hi.x, 0.f); hi.y = fmaxf(hi.y, 0.f);
                hi.z = fmaxf(hi.z, 0.f); hi.w = fmaxf(hi.w, 0.f);
            }
            *(float4*)(out + (size_t)row * NO + c0) = lo;
            *(float4*)(out + (size_t)row * NO + c0 + 4) = hi;
        }
    }
}

// ---------------- fused ReLU + per-graph max readout ----------------
__global__ void readout_kernel(const float* __restrict__ agg2, const int* __restrict__ gid,
                               unsigned* __restrict__ out, int nN) {
    const int NPW = 8;
    int wave = (int)(((unsigned)blockIdx.x * blockDim.x + threadIdx.x) >> 6);
    int lane = threadIdx.x & 63;
    int n0 = wave * NPW;
    if (n0 >= nN) return;
    int curg = gid[n0];
    float best = 0.0f;
    for (int i = 0; i < NPW; ++i) {
        int n = n0 + i;
        if (n >= nN) break;
        int g = gid[n];
        float v = fmaxf(agg2[(size_t)n * 64 + lane], 0.0f);
        if (g != curg) {
            atomicMax(&out[curg * 64 + lane], __float_as_uint(best));
            curg = g;
            best = v;
        } else {
            best = fmaxf(best, v);
        }
    }
    atomicMax(&out[curg * 64 + lane], __float_as_uint(best));
}

extern "C" void kernel_launch(void* const* d_in, const int* in_sizes, int n_in,
                              void* d_out, int out_size, void* d_ws, size_t ws_size,
                              hipStream_t stream) {
    const float* x   = (const float*)d_in[0];   // [100000, 69]
    const float* W1  = (const float*)d_in[1];   // [69, 128]
    const float* W2  = (const float*)d_in[2];   // [128, 64]
    const int*   src = (const int*)d_in[3];     // [1600000]
    const int*   dst = (const int*)d_in[4];     // [1600000]
    const int*   gid = (const int*)d_in[5];     // [100000] sorted

    const int NB_SCAN = (N_NODES + SCAN_BS - 1) / SCAN_BS;  // 98

    char* w = (char*)d_ws;
    float* isqo    = (float*)w;                 w += N_NODES * 4;
    float* isqi    = (float*)w;                 w += N_NODES * 4;
    int* cnt_src   = (int*)w;                   w += N_NODES * 4;
    int* cnt_dst   = (int*)w;                   w += N_NODES * 4;
    int* row_start = (int*)w;                   w += N_NODES * 4;
    int* cursor    = (int*)w;                   w += N_NODES * 4;
    int* blksum    = (int*)w;                   w += ((NB_SCAN + 255) / 256) * 1024;
    int* ecol      = (int*)w;                   w += (size_t)N_EDGES * 4;
    float* bufA    = (float*)w;                 w += (size_t)N_NODES * 72 * 4;  // agg1 (stride 72) -> y2 [N,64]
    float* bufB    = (float*)w;                 /* [N,128] h1 -> [N,64] agg2 */

    // zero int accumulators + output (every call: graph replays don't re-poison)
    hipMemsetAsync(cnt_src, 0, 2 * (size_t)N_NODES * sizeof(int), stream);
    hipMemsetAsync(d_out, 0, (size_t)out_size * sizeof(float), stream);

    // ----- CSR build + degree scales -----
    hist_kernel<<<(N_EDGES + 255) / 256, 256, 0, stream>>>(src, dst, cnt_src, cnt_dst, N_EDGES);
    isq_from_cnt<<<(N_NODES + 255) / 256, 256, 0, stream>>>(cnt_src, isqo, N_NODES);
    isq_from_cnt<<<(N_NODES + 255) / 256, 256, 0, stream>>>(cnt_dst, isqi, N_NODES);
    scan1<<<NB_SCAN, 256, 0, stream>>>(cnt_dst, row_start, blksum, N_NODES);
    scan2<<<1, 64, 0, stream>>>(blksum, NB_SCAN);
    scan3<<<(N_NODES + 255) / 256, 256, 0, stream>>>(row_start, blksum, cursor, N_NODES);
    reorder_kernel<<<(N_EDGES + 255) / 256, 256, 0, stream>>>(src, dst, cursor, ecol, N_EDGES);

    // ----- layer 1: gather (width 69 -> stride 72, scales fused) then GEMM(+relu) -----
    gather_kernel<69, 72><<<(N_NODES * 64 + 255) / 256, 256, 0, stream>>>(
        x, ecol, row_start, isqo, isqi, bufA, N_NODES, N_EDGES);
    node_gemm<72, 69, 128, true><<<(N_NODES + 63) / 64, 256, 0, stream>>>(bufA, W1, bufB, N_NODES);

    // ----- layer 2: GEMM first (128->64), then gather (width 64, scales fused) -----
    node_gemm<128, 128, 64, false><<<(N_NODES + 127) / 128, 256, 0, stream>>>(bufB, W2, bufA, N_NODES);
    gather_kernel<64, 64><<<(N_NODES * 64 + 255) / 256, 256, 0, stream>>>(
        bufA, ecol, row_start, isqo, isqi, bufB, N_NODES, N_EDGES);

    // ----- fused ReLU + per-graph max readout -----
    readout_kernel<<<((N_NODES + 7) / 8 * 64 + 255) / 256, 256, 0, stream>>>(
        bufB, gid, (unsigned*)d_out, N_NODES);
}

// Round 4
// 324.384 us; speedup vs baseline: 4.3252x; 1.8252x over previous
//
#include <hip/hip_runtime.h>

#define N_NODES 100000
#define N_EDGES 1600000
#define NUM_GRAPHS 128

#define BSH 7
#define NBUCK 782                 // ceil(N_NODES / 128)
#define NBLKP 256                 // partition blocks
#define EPB (N_EDGES / NBLKP)     // 6250
#define SOFF (NBUCK * NBLKP)      // src-region offset in cnt array
#define NSCAN (2 * NBUCK * NBLKP) // 400384
#define SCAN_BS 1024
#define NBSC ((NSCAN + SCAN_BS - 1) / SCAN_BS)  // 391

// ---------------- Phase A: per-block coarse histograms (dst & src) ----------------
__global__ __launch_bounds__(256) void part_hist(const int* __restrict__ src,
                                                 const int* __restrict__ dst,
                                                 int* __restrict__ cnt) {
    __shared__ int hd[NBUCK], hs[NBUCK];
    for (int i = threadIdx.x; i < NBUCK; i += 256) { hd[i] = 0; hs[i] = 0; }
    __syncthreads();
    int bk = blockIdx.x;
    int e0 = bk * EPB;
    for (int j = threadIdx.x; j < EPB; j += 256) {
        int e = e0 + j;
        atomicAdd(&hd[dst[e] >> BSH], 1);
        atomicAdd(&hs[src[e] >> BSH], 1);
    }
    __syncthreads();
    for (int i = threadIdx.x; i < NBUCK; i += 256) {
        cnt[i * NBLKP + bk] = hd[i];
        cnt[SOFF + i * NBLKP + bk] = hs[i];
    }
}

// ---------------- exclusive scan (in-place capable) ----------------
__global__ __launch_bounds__(256) void scan1(const int* __restrict__ cnt, int* __restrict__ excl,
                                             int* __restrict__ blksum, int n) {
    __shared__ int tmp[256];
    int t = threadIdx.x;
    int idx0 = blockIdx.x * SCAN_BS + t * 4;
    int v[4];
#pragma unroll
    for (int k = 0; k < 4; ++k) { int i = idx0 + k; v[k] = (i < n) ? cnt[i] : 0; }
    int sum = v[0] + v[1] + v[2] + v[3];
    tmp[t] = sum;
    __syncthreads();
    for (int off = 1; off < 256; off <<= 1) {
        int y = (t >= off) ? tmp[t - off] : 0;
        __syncthreads();
        tmp[t] += y;
        __syncthreads();
    }
    int run = (t > 0) ? tmp[t - 1] : 0;
#pragma unroll
    for (int k = 0; k < 4; ++k) { int i = idx0 + k; if (i < n) excl[i] = run; run += v[k]; }
    if (t == 255) blksum[blockIdx.x] = tmp[255];
}

__global__ __launch_bounds__(256) void scan2(int* __restrict__ blksum, int nb) {
    __shared__ int tmp[256];
    int t = threadIdx.x;
    int v[4]; int s = 0;
#pragma unroll
    for (int k = 0; k < 4; ++k) { int i = t * 4 + k; v[k] = (i < nb) ? blksum[i] : 0; s += v[k]; }
    tmp[t] = s;
    __syncthreads();
    for (int off = 1; off < 256; off <<= 1) {
        int y = (t >= off) ? tmp[t - off] : 0;
        __syncthreads();
        tmp[t] += y;
        __syncthreads();
    }
    int run = (t > 0) ? tmp[t - 1] : 0;
#pragma unroll
    for (int k = 0; k < 4; ++k) { int i = t * 4 + k; if (i < nb) { int x = v[k]; blksum[i] = run; run += x; } }
}

__global__ void scan3(int* __restrict__ excl, const int* __restrict__ blkoff, int n) {
    int i = blockIdx.x * 256 + threadIdx.x;
    if (i < n) excl[i] += blkoff[i >> 10];
}

// ---------------- Phase C: partition edges into coarse buckets (LDS cursors) ----------------
__global__ __launch_bounds__(256) void part_scatter(const int* __restrict__ src,
                                                    const int* __restrict__ dst,
                                                    const int* __restrict__ base,
                                                    unsigned* __restrict__ pdst,
                                                    unsigned char* __restrict__ psrc) {
    __shared__ int cd[NBUCK], cs[NBUCK];
    int bk = blockIdx.x;
    for (int i = threadIdx.x; i < NBUCK; i += 256) {
        cd[i] = base[i * NBLKP + bk];
        cs[i] = base[SOFF + i * NBLKP + bk] - N_EDGES;
    }
    __syncthreads();
    int e0 = bk * EPB;
    for (int j = threadIdx.x; j < EPB; j += 256) {
        int e = e0 + j;
        int s = src[e], d = dst[e];
        int pd = atomicAdd(&cd[d >> BSH], 1);
        pdst[pd] = (unsigned)s | ((unsigned)(d & 127) << 17);
        int ps = atomicAdd(&cs[s >> BSH], 1);
        psrc[ps] = (unsigned char)(s & 127);
    }
}

// ---------------- Phase D: fine CSR per bucket (128 nodes) ----------------
__global__ __launch_bounds__(256) void build_csr(const unsigned* __restrict__ pdst,
                                                 const int* __restrict__ base,
                                                 int* __restrict__ ecol, int* __restrict__ row_start,
                                                 float* __restrict__ isqi, int nN) {
    __shared__ int lh[128];
    __shared__ int lcur[128];
    int bu = blockIdx.x;
    int b0 = base[bu * NBLKP];
    int b1 = (bu == NBUCK - 1) ? N_EDGES : base[(bu + 1) * NBLKP];
    int t = threadIdx.x;
    if (t < 128) lh[t] = 0;
    __syncthreads();
    for (int j = b0 + t; j < b1; j += 256)
        atomicAdd(&lh[pdst[j] >> 17], 1);
    __syncthreads();
    int myc = (t < 128) ? lh[t] : 0;
    for (int off = 1; off < 128; off <<= 1) {
        int v = (t < 128 && t >= off) ? lh[t - off] : 0;
        __syncthreads();
        if (t < 128) lh[t] += v;
        __syncthreads();
    }
    if (t < 128) {
        int excl = lh[t] - myc;
        int node = (bu << BSH) + t;
        if (node < nN) {
            row_start[node] = b0 + excl;
            isqi[node] = rsqrtf(fmaxf((float)myc, 1.0f));
        }
        lcur[t] = b0 + excl;
    }
    __syncthreads();
    for (int j = b0 + t; j < b1; j += 256) {
        unsigned w = pdst[j];
        int off = w >> 17;
        int pos = atomicAdd(&lcur[off], 1);
        ecol[pos] = (int)(w & 0x1FFFFu);
    }
}

__global__ __launch_bounds__(256) void src_deg(const unsigned char* __restrict__ psrc,
                                               const int* __restrict__ base,
                                               float* __restrict__ isqo, int nN) {
    __shared__ int lh[128];
    int bu = blockIdx.x;
    int b0 = base[SOFF + bu * NBLKP] - N_EDGES;
    int b1 = (bu == NBUCK - 1) ? N_EDGES : base[SOFF + (bu + 1) * NBLKP] - N_EDGES;
    int t = threadIdx.x;
    if (t < 128) lh[t] = 0;
    __syncthreads();
    for (int j = b0 + t; j < b1; j += 256)
        atomicAdd(&lh[psrc[j]], 1);
    __syncthreads();
    if (t < 128) {
        int node = (bu << BSH) + t;
        if (node < nN) isqo[node] = rsqrtf(fmaxf((float)lh[t], 1.0f));
    }
}

// ---------------- pre-scale x by isqo into stride-72 padded buffer ----------------
__global__ void prescale_kernel(const float* __restrict__ x, const float* __restrict__ isqo,
                                float* __restrict__ xs, int nN) {
    int wave = (int)(((unsigned)blockIdx.x * blockDim.x + threadIdx.x) >> 6);
    int lane = threadIdx.x & 63;
    if (wave >= nN) return;
    float sc = isqo[wave];
    xs[(size_t)wave * 72 + lane] = x[(size_t)wave * 69 + lane] * sc;
    if (lane < 8)
        xs[(size_t)wave * 72 + 64 + lane] =
            (lane < 5) ? x[(size_t)wave * 69 + 64 + lane] * sc : 0.0f;
}

// ---------------- gather: agg[n] = dscale[n] * sum_{e in row n} feat[src_e] ----------------
template<int D>
__global__ void gather_kernel(const float* __restrict__ feat, const int* __restrict__ ecol,
                              const int* __restrict__ row_start, const float* __restrict__ dscale,
                              float* __restrict__ agg, int nN, int nE) {
    int wave = (int)(((unsigned)blockIdx.x * blockDim.x + threadIdx.x) >> 6);
    int lane = threadIdx.x & 63;
    if (wave >= nN) return;
    int beg = row_start[wave];
    int end = (wave == nN - 1) ? nE : row_start[wave + 1];
    float acc0 = 0.0f, acc1 = 0.0f;
    for (int j0 = beg; j0 < end; j0 += 64) {
        int ne = min(64, end - j0);
        int eidx = (lane < ne) ? ecol[j0 + lane] : 0;
        int k = 0;
        for (; k + 4 <= ne; k += 4) {
            int s0 = __shfl(eidx, k),     s1 = __shfl(eidx, k + 1);
            int s2 = __shfl(eidx, k + 2), s3 = __shfl(eidx, k + 3);
            const float* f0 = feat + (size_t)s0 * D;
            const float* f1 = feat + (size_t)s1 * D;
            const float* f2 = feat + (size_t)s2 * D;
            const float* f3 = feat + (size_t)s3 * D;
            float a0 = f0[lane], a1 = f1[lane], a2 = f2[lane], a3 = f3[lane];
            if (D > 64 && lane < D - 64)
                acc1 += (f0[64 + lane] + f1[64 + lane]) + (f2[64 + lane] + f3[64 + lane]);
            acc0 += (a0 + a1) + (a2 + a3);
        }
        for (; k < ne; ++k) {
            int s = __shfl(eidx, k);
            const float* fr = feat + (size_t)s * D;
            acc0 += fr[lane];
            if (D > 64 && lane < D - 64) acc1 += fr[64 + lane];
        }
    }
    float dsc = dscale[wave];
    agg[(size_t)wave * D + lane] = acc0 * dsc;
    if (D > 64 && lane < D - 64) agg[(size_t)wave * D + 64 + lane] = acc1 * dsc;
}

// ---------------- register-blocked node GEMM ----------------
template<int KP, int K, int NO, bool RELU, bool SCALE>
__global__ __launch_bounds__(256) void node_gemm(const float* __restrict__ in,
                                                 const float* __restrict__ W,
                                                 const float* __restrict__ rowscale,
                                                 float* __restrict__ out, int nN) {
    constexpr int CG = NO / 8;
    constexpr int RT = 256 / CG;
    constexpr int ROWS = RT * 4;
    __shared__ float Wl[KP * NO];
    for (int i = threadIdx.x; i < KP * NO; i += 256)
        Wl[i] = (i < K * NO) ? W[i] : 0.0f;
    __syncthreads();

    int cg = threadIdx.x % CG;
    int rt = threadIdx.x / CG;
    int row0 = blockIdx.x * ROWS + rt * 4;
    int c0 = cg * 8;

    float4 accL[4] = {};
    float4 accH[4] = {};
    int rclamp[4];
#pragma unroll
    for (int r = 0; r < 4; ++r) rclamp[r] = min(row0 + r, nN - 1);

#pragma unroll 2
    for (int k4 = 0; k4 < KP / 4; ++k4) {
        float4 a[4];
#pragma unroll
        for (int r = 0; r < 4; ++r)
            a[r] = *(const float4*)(in + (size_t)rclamp[r] * KP + k4 * 4);
#pragma unroll
        for (int kk = 0; kk < 4; ++kk) {
            int k = k4 * 4 + kk;
            float4 wlo = *(const float4*)&Wl[k * NO + c0];
            float4 whi = *(const float4*)&Wl[k * NO + c0 + 4];
#pragma unroll
            for (int r = 0; r < 4; ++r) {
                float ar = (kk == 0) ? a[r].x : (kk == 1) ? a[r].y : (kk == 2) ? a[r].z : a[r].w;
                accL[r].x += ar * wlo.x; accL[r].y += ar * wlo.y;
                accL[r].z += ar * wlo.z; accL[r].w += ar * wlo.w;
                accH[r].x += ar * whi.x; accH[r].y += ar * whi.y;
                accH[r].z += ar * whi.z; accH[r].w += ar * whi.w;
            }
        }
    }

#pragma unroll
    for (int r = 0; r < 4; ++r) {
        int row = row0 + r;
        if (row < nN) {
            float4 lo = accL[r], hi = accH[r];
            if (SCALE) {
                float sc = rowscale[row];
                lo.x *= sc; lo.y *= sc; lo.z *= sc; lo.w *= sc;
                hi.x *= sc; hi.y *= sc; hi.z *= sc; hi.w *= sc;
            }
            if (RELU) {
                lo.x = fmaxf(lo.x, 0.f); lo.y = fmaxf(lo.y, 0.f);
                lo.z = fmaxf(lo.z, 0.f); lo.w = fmaxf(lo.w, 0.f);
                hi.x = fmaxf(hi.x, 0.f); hi.y = fmaxf(hi.y, 0.f);
                hi.z = fmaxf(hi.z, 0.f); hi.w = fmaxf(hi.w, 0.f);
            }
            *(float4*)(out + (size_t)row * NO + c0) = lo;
            *(float4*)(out + (size_t)row * NO + c0 + 4) = hi;
        }
    }
}

// ---------------- fused ReLU + per-graph max readout ----------------
__global__ void readout_kernel(const float* __restrict__ agg2, const int* __restrict__ gid,
                               unsigned* __restrict__ out, int nN) {
    const int NPW = 8;
    int wave = (int)(((unsigned)blockIdx.x * blockDim.x + threadIdx.x) >> 6);
    int lane = threadIdx.x & 63;
    int n0 = wave * NPW;
    if (n0 >= nN) return;
    int curg = gid[n0];
    float best = 0.0f;
    for (int i = 0; i < NPW; ++i) {
        int n = n0 + i;
        if (n >= nN) break;
        int g = gid[n];
        float v = fmaxf(agg2[(size_t)n * 64 + lane], 0.0f);
        if (g != curg) {
            atomicMax(&out[curg * 64 + lane], __float_as_uint(best));
            curg = g;
            best = v;
        } else {
            best = fmaxf(best, v);
        }
    }
    atomicMax(&out[curg * 64 + lane], __float_as_uint(best));
}

extern "C" void kernel_launch(void* const* d_in, const int* in_sizes, int n_in,
                              void* d_out, int out_size, void* d_ws, size_t ws_size,
                              hipStream_t stream) {
    const float* x   = (const float*)d_in[0];   // [100000, 69]
    const float* W1  = (const float*)d_in[1];   // [69, 128]
    const float* W2  = (const float*)d_in[2];   // [128, 64]
    const int*   src = (const int*)d_in[3];     // [1600000]
    const int*   dst = (const int*)d_in[4];     // [1600000]
    const int*   gid = (const int*)d_in[5];     // [100000] sorted

    char* w = (char*)d_ws;
    float* isqo    = (float*)w;                 w += N_NODES * 4;
    float* isqi    = (float*)w;                 w += N_NODES * 4;
    int* row_start = (int*)w;                   w += N_NODES * 4;
    int* ecol      = (int*)w;                   w += (size_t)N_EDGES * 4;
    int* cnt       = (int*)w;                   w += (size_t)NSCAN * 4;      // count matrix -> scanned bases (in place)
    int* blksum    = (int*)w;                   w += 1024 * 4;
    float* bufA    = (float*)w;                 w += (size_t)N_NODES * 72 * 4;  // agg1 -> y2s
    float* bufB    = (float*)w;                 // 51.2MB region, time-shared:
    unsigned* pdst      = (unsigned*)bufB;                            // [nE] u32, dead after build_csr
    unsigned char* psrc = (unsigned char*)(bufB) + (size_t)N_EDGES * 4; // [nE] u8, dead after src_deg
    float* xs = bufB;                                                 // [N,72], prescale..gather1
    // bufB proper (h1 [N,128] then agg2 [N,64]) starts life at gemm1

    hipMemsetAsync(d_out, 0, (size_t)out_size * sizeof(float), stream);

    // ----- two-level CSR build, no global atomics -----
    part_hist<<<NBLKP, 256, 0, stream>>>(src, dst, cnt);
    scan1<<<NBSC, 256, 0, stream>>>(cnt, cnt, blksum, NSCAN);
    scan2<<<1, 256, 0, stream>>>(blksum, NBSC);
    scan3<<<(NSCAN + 255) / 256, 256, 0, stream>>>(cnt, blksum, NSCAN);
    part_scatter<<<NBLKP, 256, 0, stream>>>(src, dst, cnt, pdst, psrc);
    build_csr<<<NBUCK, 256, 0, stream>>>(pdst, cnt, ecol, row_start, isqi, N_NODES);
    src_deg<<<NBUCK, 256, 0, stream>>>(psrc, cnt, isqo, N_NODES);

    // ----- layer 1: prescale -> gather(72) -> GEMM(+relu) -----
    prescale_kernel<<<(N_NODES * 64 + 255) / 256, 256, 0, stream>>>(x, isqo, xs, N_NODES);
    gather_kernel<72><<<(N_NODES * 64 + 255) / 256, 256, 0, stream>>>(
        xs, ecol, row_start, isqi, bufA, N_NODES, N_EDGES);
    node_gemm<72, 69, 128, true, false><<<(N_NODES + 63) / 64, 256, 0, stream>>>(
        bufA, W1, nullptr, bufB, N_NODES);

    // ----- layer 2: GEMM(*isqo) -> gather(64) -----
    node_gemm<128, 128, 64, false, true><<<(N_NODES + 127) / 128, 256, 0, stream>>>(
        bufB, W2, isqo, bufA, N_NODES);
    gather_kernel<64><<<(N_NODES * 64 + 255) / 256, 256, 0, stream>>>(
        bufA, ecol, row_start, isqi, bufB, N_NODES, N_EDGES);

    // ----- fused ReLU + per-graph max readout -----
    readout_kernel<<<((N_NODES + 7) / 8 * 64 + 255) / 256, 256, 0, stream>>>(
        bufB, gid, (unsigned*)d_out, N_NODES);
}